// Round 12
// baseline (657.236 us; speedup 1.0000x reference)
//
#include <hip/hip_runtime.h>

#define BB 1024
#define TT 512
#define KK 64

__global__ void crf_zero_loss(float* out) {
    out[(size_t)BB * TT] = 0.0f;
}

// combine (v,i); ties -> lower index (jnp.argmax first-occurrence)
#define COMB(v, i, v2, i2)                                   \
    { bool _t = ((v2) > (v)) || ((v2) == (v) && (i2) < (i)); \
      (v) = _t ? (v2) : (v); (i) = _t ? (i2) : (i); }

// tree-scan step: value chain via fmaxf (no VCC in chain), index select off-chain
#define VSTEP(bv, bi, aval, ii)                              \
    { float _s = (aval) + tc[ii]; bool _g = _s > (bv);       \
      (bv) = fmaxf((bv), _s); (bi) = _g ? (ii) : (bi); }

__global__ __launch_bounds__(128, 1)
void crf_fwd_kernel(const float* __restrict__ logits,
                    const int* __restrict__ nwords,
                    const int* __restrict__ tags,
                    const float* __restrict__ trans,
                    float* __restrict__ out) {
    __shared__ __align__(16) float sA[KK];        // viterbi alpha broadcast
    __shared__ __align__(16) float sU[KK];        // exp-domain lse state broadcast
    __shared__ unsigned char sBP[TT * KK];        // backpointers
    __shared__ unsigned char sTag[TT];            // backtraced tags staging

    const int b    = blockIdx.x;
    const int lane = threadIdx.x & 63;
    const int wid  = threadIdx.x >> 6;
    const int len  = nwords[b];
    const float* lg = logits + (size_t)b * TT * KK;

    if (wid == 0) {
        // ---------------- Viterbi wave: 8-slot tree argmax + 2-ahead prefetch ----------------
        float tc[KK];
#pragma unroll
        for (int i = 0; i < KK; ++i) tc[i] = trans[i * KK + lane];

        float alpha = lg[lane];          // t = 0
        sA[lane] = alpha;

        float f1 = lg[(len > 1 ? 1 : 0) * KK + lane];
        float f2 = lg[(len > 2 ? 2 : (len > 1 ? 1 : 0)) * KK + lane];

        for (int t = 1; t < len; ++t) {
            const float logit = f1;      // row t, prefetched 2 iterations ago
            f1 = f2;
            int tn = t + 2; if (tn > len - 1) tn = len - 1;
            f2 = lg[tn * KK + lane];     // issue early, consumed 2 steps later

            // slots: slot = (q&1)*4 + c over reads q=0..15, i = 4q+c (ascending i per slot)
            float4 ae = ((const float4*)sA)[0];
            float4 ao = ((const float4*)sA)[1];
            float bv0 = ae.x + tc[0]; int bi0 = 0;
            float bv1 = ae.y + tc[1]; int bi1 = 1;
            float bv2 = ae.z + tc[2]; int bi2 = 2;
            float bv3 = ae.w + tc[3]; int bi3 = 3;
            float bv4 = ao.x + tc[4]; int bi4 = 4;
            float bv5 = ao.y + tc[5]; int bi5 = 5;
            float bv6 = ao.z + tc[6]; int bi6 = 6;
            float bv7 = ao.w + tc[7]; int bi7 = 7;
#pragma unroll
            for (int q = 2; q < 16; q += 2) {
                ae = ((const float4*)sA)[q];
                ao = ((const float4*)sA)[q + 1];
                VSTEP(bv0, bi0, ae.x, 4*q + 0);
                VSTEP(bv1, bi1, ae.y, 4*q + 1);
                VSTEP(bv2, bi2, ae.z, 4*q + 2);
                VSTEP(bv3, bi3, ae.w, 4*q + 3);
                VSTEP(bv4, bi4, ao.x, 4*q + 4);
                VSTEP(bv5, bi5, ao.y, 4*q + 5);
                VSTEP(bv6, bi6, ao.z, 4*q + 6);
                VSTEP(bv7, bi7, ao.w, 4*q + 7);
            }
            // 3-level index-aware merge (ties -> lower index)
            COMB(bv0, bi0, bv1, bi1); COMB(bv2, bi2, bv3, bi3);
            COMB(bv4, bi4, bv5, bi5); COMB(bv6, bi6, bv7, bi7);
            COMB(bv0, bi0, bv2, bi2); COMB(bv4, bi4, bv6, bi6);
            COMB(bv0, bi0, bv4, bi4);

            alpha = bv0 + logit;
            sBP[t * KK + lane] = (unsigned char)bi0;
            sA[lane] = alpha;            // same-wave LDS ops are in-order
        }

        // last = first-occurrence argmax over lanes of alpha
        float v = alpha;
        int   idx = lane;
#pragma unroll
        for (int m = 32; m >= 1; m >>= 1) {
            const float ov = __shfl_xor(v, m);
            const int   oi = __shfl_xor(idx, m);
            COMB(v, idx, ov, oi);
        }
        const int last = idx;            // wave-uniform

        // tail: positions len-1 .. T-1 are all `last`
        for (int t = len - 1 + lane; t < TT; t += 64)
            out[(size_t)b * TT + t] = (float)last;

        // backtrace through LDS backpointers (uniform broadcast byte reads)
        int tag = last;
        for (int t = len - 1; t >= 1; --t) {
            tag = sBP[t * KK + tag];
            sTag[t - 1] = (unsigned char)tag;
        }
        // coalesced prediction writes for 0 .. len-2
        for (int t = lane; t < len - 1; t += 64)
            out[(size_t)b * TT + t] = (float)sTag[t];

    } else {
        // ---------------- exp-domain LSE wave + hoisted score (R8, unchanged) ----------------
        float E[KK];                     // exp(trans[:, lane])
#pragma unroll
        for (int i = 0; i < KK; ++i) E[i] = __expf(trans[i * KK + lane]);

        // ---- sequence score: fully parallel over t (off the recurrence) ----
        const int bT = b * TT;
        float sc = 0.0f;
        for (int t = lane; t < len; t += 64) {
            const int tg = tags[bT + t];
            sc += lg[t * KK + tg];                              // unary
            if (t + 1 < len) sc += trans[tg * KK + tags[bT + t + 1]];  // binary
        }
#pragma unroll
        for (int m = 32; m >= 1; m >>= 1) sc += __shfl_xor(sc, m);

        // ---- exp-domain forward recurrence ----
        const float lg0 = lg[lane];
        float M = lg0;
#pragma unroll
        for (int m = 32; m >= 1; m >>= 1) M = fmaxf(M, __shfl_xor(M, m));
        float C = M;                     // accumulated log-offset (wave-uniform)
        float u = __expf(lg0 - M);       // u[lane] = exp(alpha[lane] - C)
        sU[lane] = u;

        for (int t = 1; t < len; ++t) {
            const float logit = lg[t * KK + lane];

            float s0 = 0.f, s1 = 0.f, s2 = 0.f, s3 = 0.f;
#pragma unroll
            for (int q = 0; q < KK / 4; ++q) {
                const float4 u4 = reinterpret_cast<const float4*>(sU)[q];
                s0 = fmaf(u4.x, E[4*q+0], s0);
                s1 = fmaf(u4.y, E[4*q+1], s1);
                s2 = fmaf(u4.z, E[4*q+2], s2);
                s3 = fmaf(u4.w, E[4*q+3], s3);
            }
            u = ((s0 + s1) + (s2 + s3)) * __expf(logit);

            if ((t & 7) == 0) {          // deferred rescale (overflow-safe within 8 steps)
                float mx = u;
#pragma unroll
                for (int m = 32; m >= 1; m >>= 1) mx = fmaxf(mx, __shfl_xor(mx, m));
                u *= (1.0f / mx);
                C += __logf(mx);
            }
            sU[lane] = u;                // same-wave LDS ops are in-order
        }

        // log_norm = C + logsumexp(u)
        float mx = u;
#pragma unroll
        for (int m = 32; m >= 1; m >>= 1) mx = fmaxf(mx, __shfl_xor(mx, m));
        float e = u * (1.0f / mx);
#pragma unroll
        for (int m = 32; m >= 1; m >>= 1) e += __shfl_xor(e, m);
        const float log_norm = C + __logf(mx) + __logf(e);

        if (lane == 0)
            atomicAdd(out + (size_t)BB * TT, (log_norm - sc) * (1.0f / BB));
    }
}

extern "C" void kernel_launch(void* const* d_in, const int* in_sizes, int n_in,
                              void* d_out, int out_size, void* d_ws, size_t ws_size,
                              hipStream_t stream) {
    const float* logits = (const float*)d_in[0];
    const int*   nwords = (const int*)d_in[1];
    const int*   tags   = (const int*)d_in[2];
    const float* trans  = (const float*)d_in[3];
    float*       out    = (float*)d_out;

    crf_zero_loss<<<1, 1, 0, stream>>>(out);
    crf_fwd_kernel<<<BB, 128, 0, stream>>>(logits, nwords, tags, trans, out);
}